// Round 1
// baseline (6201.891 us; speedup 1.0000x reference)
//
#include <hip/hip_runtime.h>
#include <math.h>

// Problem sizes (fixed): B=16, M=256, N=256, C=64, OUT=64, modes=32, FF_HID=256
#define TWO_PI_OVER_256 0.024543692606170259f

// ws float offsets
#define WS_CTAB 0        // ctabT[n*32+k] = cos(2pi*k*n/256)
#define WS_STAB 8192     // stabT[n*32+k] = sin(2pi*k*n/256)
#define WS_W1RE 16384    // w1re_t[k*4096 + c*64 + o]
#define WS_W1IM 147456
#define WS_W2RE 278528
#define WS_W2IM 409600
#define WS_FW1T 540672   // ffw1_t[j*64 + c]
// total ws floats = 557056 (~2.2 MB)

__global__ __launch_bounds__(256) void trig_init(float* __restrict__ ws) {
    int id = blockIdx.x * 256 + threadIdx.x;   // 8192 threads
    int k = id >> 8, n = id & 255;
    // exact integer angle reduction: argument stays in [0, 2pi)
    float th = (float)((k * n) & 255) * TWO_PI_OVER_256;
    ws[WS_CTAB + n * 32 + k] = cosf(th);
    ws[WS_STAB + n * 32 + k] = sinf(th);
}

__global__ __launch_bounds__(256) void prep_weights(
        const float* __restrict__ w1re, const float* __restrict__ w1im,
        const float* __restrict__ w2re, const float* __restrict__ w2im,
        const float* __restrict__ ffw1, float* __restrict__ ws) {
    int tid = blockIdx.x * 256 + threadIdx.x;  // 540672 total
    if (tid < 524288) {
        // transpose [c][o][k] -> [k][c][o] for coalesced lane-o reads
        int r = tid & 131071;
        int w = tid >> 17;
        int o = r & 63, cc = (r >> 6) & 63, k = r >> 12;
        const float* src = (w == 0) ? w1re : (w == 1) ? w1im : (w == 2) ? w2re : w2im;
        ws[WS_W1RE + tid] = src[cc * 2048 + o * 32 + k];
    } else {
        // ff_w1 [c][j] -> [j][c] for contiguous per-j float4 reads
        int r = tid - 524288;                   // 16384
        int cc = r & 63, j = r >> 6;
        ws[WS_FW1T + r] = ffw1[cc * 256 + j];
    }
}

// One workgroup per slab (4096 slabs). STRIDE=64: y-branch, slab = x[b,m,:,:]
// (fully contiguous). STRIDE=16384: x-branch, slab = x[b,:,n,:] (64-float rows,
// 64 KB apart). ACC: add into io (io already holds the y-branch output).
template<int STRIDE, bool ACC>
__global__ __launch_bounds__(256) void spectral_pass(
        const float* __restrict__ x, float* io,
        const float* __restrict__ ws, int wre_off, int wim_off) {
    __shared__ float Xre[32 * 64], Xim[32 * 64];  // [k*64+c]
    __shared__ float Ar[32 * 64], Ai[32 * 64];    // [k*64+o], pre-scaled
    int t = threadIdx.x;
    size_t off;
    if (STRIDE == 64) {
        off = (size_t)blockIdx.x * 16384;                       // (b*256+m)*N*C
    } else {
        int b = blockIdx.x >> 8, n = blockIdx.x & 255;
        off = (size_t)b * 4194304 + (size_t)n * 64;             // b*M*N*C + n*C
    }
    const float* xb = x + off;
    float* iob = io + off;
    const float* ct = ws + WS_CTAB;
    const float* st = ws + WS_STAB;

    // ---- step 1: forward transform. lane c = t&63, wave handles 8 k's.
    {
        int c = t & 63;
        int kb = (t >> 6) * 8;
        float r0=0,r1=0,r2=0,r3=0,r4=0,r5=0,r6=0,r7=0;
        float i0=0,i1=0,i2=0,i3=0,i4=0,i5=0,i6=0,i7=0;
        for (int p = 0; p < 256; ++p) {
            float v = xb[(size_t)p * STRIDE + c];
            const float4* c4 = (const float4*)(ct + p * 32 + kb);
            const float4* s4 = (const float4*)(st + p * 32 + kb);
            float4 cA = c4[0], cB = c4[1];
            float4 sA = s4[0], sB = s4[1];
            r0 += cA.x * v; r1 += cA.y * v; r2 += cA.z * v; r3 += cA.w * v;
            r4 += cB.x * v; r5 += cB.y * v; r6 += cB.z * v; r7 += cB.w * v;
            i0 += sA.x * v; i1 += sA.y * v; i2 += sA.z * v; i3 += sA.w * v;
            i4 += sB.x * v; i5 += sB.y * v; i6 += sB.z * v; i7 += sB.w * v;
        }
        // rfft ortho: /sqrt(256); e^{-i t}: imag gets minus
        Xre[(kb+0)*64+c] = r0 * 0.0625f;  Xim[(kb+0)*64+c] = i0 * -0.0625f;
        Xre[(kb+1)*64+c] = r1 * 0.0625f;  Xim[(kb+1)*64+c] = i1 * -0.0625f;
        Xre[(kb+2)*64+c] = r2 * 0.0625f;  Xim[(kb+2)*64+c] = i2 * -0.0625f;
        Xre[(kb+3)*64+c] = r3 * 0.0625f;  Xim[(kb+3)*64+c] = i3 * -0.0625f;
        Xre[(kb+4)*64+c] = r4 * 0.0625f;  Xim[(kb+4)*64+c] = i4 * -0.0625f;
        Xre[(kb+5)*64+c] = r5 * 0.0625f;  Xim[(kb+5)*64+c] = i5 * -0.0625f;
        Xre[(kb+6)*64+c] = r6 * 0.0625f;  Xim[(kb+6)*64+c] = i6 * -0.0625f;
        Xre[(kb+7)*64+c] = r7 * 0.0625f;  Xim[(kb+7)*64+c] = i7 * -0.0625f;
    }
    __syncthreads();

    // ---- step 2: per-frequency complex channel mix. lane o = t&63.
    {
        int o = t & 63;
        int kb = (t >> 6) * 8;
        const float* wre = ws + wre_off;
        const float* wim = ws + wim_off;
        for (int kk = 0; kk < 8; ++kk) {
            int k = kb + kk;
            const float* wr = wre + k * 4096 + o;
            const float* wi = wim + k * 4096 + o;
            const float* xr = Xre + k * 64;
            const float* xi = Xim + k * 64;
            float a0=0, a1=0, b0=0, b1=0;
            #pragma unroll 4
            for (int q = 0; q < 16; ++q) {
                float4 xrv = *(const float4*)(xr + q * 4);
                float4 xiv = *(const float4*)(xi + q * 4);
                float w0 = wr[(q*4+0)*64], w1v = wr[(q*4+1)*64];
                float w2v = wr[(q*4+2)*64], w3v = wr[(q*4+3)*64];
                float u0 = wi[(q*4+0)*64], u1 = wi[(q*4+1)*64];
                float u2 = wi[(q*4+2)*64], u3 = wi[(q*4+3)*64];
                a0 += xrv.x*w0 + xrv.y*w1v + xrv.z*w2v + xrv.w*w3v;
                a1 -= xiv.x*u0 + xiv.y*u1 + xiv.z*u2 + xiv.w*u3;
                b0 += xrv.x*u0 + xrv.y*u1 + xrv.z*u2 + xrv.w*u3;
                b1 += xiv.x*w0 + xiv.y*w1v + xiv.z*w2v + xiv.w*w3v;
            }
            // fold irfft ortho 1/16 and the 2x for k>=1 here
            float sc = (k == 0) ? 0.0625f : 0.125f;
            Ar[k*64+o] = (a0 + a1) * sc;
            Ai[k*64+o] = (b0 + b1) * sc;
        }
    }
    __syncthreads();

    // ---- step 3: inverse transform + store. lane o = t&63, wave owns 64 p's.
    {
        int o = t & 63;
        int pb = (t >> 6) * 64;
        float arr[32], aii[32];
        #pragma unroll
        for (int k = 0; k < 32; ++k) {
            arr[k] = Ar[k*64+o];
            aii[k] = Ai[k*64+o];
        }
        for (int p = pb; p < pb + 64; ++p) {
            const float4* c4 = (const float4*)(ct + p * 32);
            const float4* s4 = (const float4*)(st + p * 32);
            float a0=0, a1=0, a2=0, a3=0;
            #pragma unroll
            for (int q = 0; q < 8; ++q) {
                float4 cv = c4[q], sv = s4[q];
                a0 += arr[q*4+0]*cv.x - aii[q*4+0]*sv.x;
                a1 += arr[q*4+1]*cv.y - aii[q*4+1]*sv.y;
                a2 += arr[q*4+2]*cv.z - aii[q*4+2]*sv.z;
                a3 += arr[q*4+3]*cv.w - aii[q*4+3]*sv.w;
            }
            float r = (a0 + a1) + (a2 + a3);
            size_t adr = (size_t)p * STRIDE + o;
            if (ACC) r += iob[adr];   // same thread read+write, no hazard
            iob[adr] = r;
        }
    }
}

// Thread-per-token FF (64 -> 256 relu -> 64) + LayerNorm, in-place on io.
__global__ __launch_bounds__(256) void ff_ln(
        const float* __restrict__ ws, float* io,
        const float* __restrict__ ffw2, const float* __restrict__ ffb1,
        const float* __restrict__ ffb2, const float* __restrict__ lng,
        const float* __restrict__ lnb) {
    size_t tok = (size_t)blockIdx.x * 256 + threadIdx.x;   // 1048576 tokens
    float* xp = io + tok * 64;
    float xv[64];
    #pragma unroll
    for (int q = 0; q < 16; ++q) {
        float4 v = ((const float4*)xp)[q];
        xv[q*4+0]=v.x; xv[q*4+1]=v.y; xv[q*4+2]=v.z; xv[q*4+3]=v.w;
    }
    float y[64];
    #pragma unroll
    for (int q = 0; q < 16; ++q) {
        float4 v = ((const float4*)ffb2)[q];
        y[q*4+0]=v.x; y[q*4+1]=v.y; y[q*4+2]=v.z; y[q*4+3]=v.w;
    }
    const float* w1t = ws + WS_FW1T;
    for (int j = 0; j < 256; ++j) {
        const float4* w1 = (const float4*)(w1t + j * 64);
        float h0 = ffb1[j], h1 = 0.f, h2 = 0.f, h3 = 0.f;
        #pragma unroll
        for (int q = 0; q < 4; ++q) {
            float4 a = w1[q*4+0], b = w1[q*4+1], c = w1[q*4+2], d = w1[q*4+3];
            h0 += xv[q*16+ 0]*a.x + xv[q*16+ 1]*a.y + xv[q*16+ 2]*a.z + xv[q*16+ 3]*a.w;
            h1 += xv[q*16+ 4]*b.x + xv[q*16+ 5]*b.y + xv[q*16+ 6]*b.z + xv[q*16+ 7]*b.w;
            h2 += xv[q*16+ 8]*c.x + xv[q*16+ 9]*c.y + xv[q*16+10]*c.z + xv[q*16+11]*c.w;
            h3 += xv[q*16+12]*d.x + xv[q*16+13]*d.y + xv[q*16+14]*d.z + xv[q*16+15]*d.w;
        }
        float h = fmaxf((h0 + h1) + (h2 + h3), 0.f);
        const float4* w2 = (const float4*)(ffw2 + j * 64);
        #pragma unroll
        for (int q = 0; q < 16; ++q) {
            float4 wv = w2[q];
            y[q*4+0] += h*wv.x; y[q*4+1] += h*wv.y;
            y[q*4+2] += h*wv.z; y[q*4+3] += h*wv.w;
        }
    }
    // LayerNorm over 64
    float s0=0,s1=0,s2=0,s3=0;
    #pragma unroll
    for (int q = 0; q < 16; ++q) { s0+=y[q*4+0]; s1+=y[q*4+1]; s2+=y[q*4+2]; s3+=y[q*4+3]; }
    float mu = ((s0+s1)+(s2+s3)) * 0.015625f;
    float v0=0,v1=0,v2=0,v3=0;
    #pragma unroll
    for (int q = 0; q < 16; ++q) {
        float d0=y[q*4+0]-mu, d1=y[q*4+1]-mu, d2=y[q*4+2]-mu, d3=y[q*4+3]-mu;
        v0+=d0*d0; v1+=d1*d1; v2+=d2*d2; v3+=d3*d3;
    }
    float rs = rsqrtf(((v0+v1)+(v2+v3)) * 0.015625f + 1e-5f);
    #pragma unroll
    for (int q = 0; q < 16; ++q) {
        float4 g = ((const float4*)lng)[q];
        float4 bb = ((const float4*)lnb)[q];
        float4 r;
        r.x = (y[q*4+0]-mu)*rs*g.x + bb.x;
        r.y = (y[q*4+1]-mu)*rs*g.y + bb.y;
        r.z = (y[q*4+2]-mu)*rs*g.z + bb.z;
        r.w = (y[q*4+3]-mu)*rs*g.w + bb.w;
        ((float4*)xp)[q] = r;
    }
}

extern "C" void kernel_launch(void* const* d_in, const int* in_sizes, int n_in,
                              void* d_out, int out_size, void* d_ws, size_t ws_size,
                              hipStream_t stream) {
    (void)in_sizes; (void)n_in; (void)out_size; (void)ws_size;
    const float* x    = (const float*)d_in[0];
    const float* w1re = (const float*)d_in[1];
    const float* w1im = (const float*)d_in[2];
    const float* w2re = (const float*)d_in[3];
    const float* w2im = (const float*)d_in[4];
    const float* ffw1 = (const float*)d_in[5];
    const float* ffb1 = (const float*)d_in[6];
    const float* ffw2 = (const float*)d_in[7];
    const float* ffb2 = (const float*)d_in[8];
    const float* lng  = (const float*)d_in[9];
    const float* lnb  = (const float*)d_in[10];
    float* out = (float*)d_out;
    float* ws  = (float*)d_ws;

    trig_init<<<32, 256, 0, stream>>>(ws);
    prep_weights<<<2112, 256, 0, stream>>>(w1re, w1im, w2re, w2im, ffw1, ws);
    // y-branch: writes xy into d_out (scratch)
    spectral_pass<64, false><<<4096, 256, 0, stream>>>(x, out, ws, WS_W1RE, WS_W1IM);
    // x-branch: accumulates xx into d_out
    spectral_pass<16384, true><<<4096, 256, 0, stream>>>(x, out, ws, WS_W2RE, WS_W2IM);
    // FF + LayerNorm in place
    ff_ln<<<4096, 256, 0, stream>>>(ws, out, ffw2, ffb1, ffb2, lng, lnb);
}